// Round 4
// baseline (403.209 us; speedup 1.0000x reference)
//
#include <hip/hip_runtime.h>

static constexpr float SLOPE = 0.2f;

#define NPB 256          // nodes per bucket
#define CAP 10240        // packed-edge capacity per bucket (avg ~8192, >20 sigma margin)
#define EPB 8192         // edges per bin block

// Fixed-point scale for order-independent integer accumulation (2^42).
static constexpr float FPSCALE = 4398046511104.f;

// ---------------------------------------------------------------------------
// Detect whether edge_index buffer is int64 or int32 (JAX x64 on/off).
__global__ void detect_kernel(const unsigned int* __restrict__ ei, int* __restrict__ flag) {
    __shared__ int nz;
    if (threadIdx.x == 0) nz = 0;
    __syncthreads();
    if (ei[2 * threadIdx.x + 1] != 0u) atomicOr(&nz, 1);
    __syncthreads();
    if (threadIdx.x == 0) *flag = (nz == 0) ? 1 : 0;
}

__device__ __forceinline__ int load_idx(const void* ei, int is64, long long pos) {
    return is64 ? (int)((const long long*)ei)[pos] : ((const int*)ei)[pos];
}

// ---------------------------------------------------------------------------
// Pass 1: bin edges by dst bucket. Per-block LDS histogram -> bulk reservation
// -> append packed (dst_local<<17 | src) into per-bucket regions. Order within
// a bucket region is schedule-dependent; harmless because aggregation is
// bitwise order-independent (int64 fixed-point sums, exact max).
__global__ void bin_kernel(const void* __restrict__ ei, const int* __restrict__ flag,
                           int* __restrict__ bfill, unsigned int* __restrict__ packed,
                           int e, int nb) {
    __shared__ int hist[512];
    __shared__ int base[512];
    int t = threadIdx.x;
    for (int i = t; i < nb; i += 256) hist[i] = 0;
    __syncthreads();
    long long e0 = (long long)blockIdx.x * EPB;
    int cnt = (int)min((long long)EPB, (long long)e - e0);
    int is64 = *flag;
    // phase A: histogram of dst buckets
    for (int i = t; i < cnt; i += 256) {
        int d = load_idx(ei, is64, (long long)e + e0 + i);
        atomicAdd(&hist[d >> 8], 1);
    }
    __syncthreads();
    // reserve global ranges; reuse hist as local cursor
    for (int i = t; i < nb; i += 256) {
        int c = hist[i];
        base[i] = c ? atomicAdd(&bfill[i], c) : 0;
        hist[i] = 0;
    }
    __syncthreads();
    // phase B: place (dst chunk re-read hits L2)
    for (int i = t; i < cnt; i += 256) {
        int s = load_idx(ei, is64, e0 + i);
        int d = load_idx(ei, is64, (long long)e + e0 + i);
        int bk = d >> 8;
        int lp = atomicAdd(&hist[bk], 1);
        int pos = base[bk] + lp;
        if (pos < CAP)
            packed[(long long)bk * CAP + pos] = ((unsigned)(d & 255) << 17) | (unsigned)s;
    }
}

// ---------------------------------------------------------------------------
// Exclusive scan over bucket fills -> csr base per bucket.
__global__ void bscan_kernel(const int* __restrict__ bfill, int* __restrict__ boffs, int nb) {
    __shared__ int tmp[512];
    int t = threadIdx.x;
    int v = (t < nb) ? min(bfill[t], CAP) : 0;
    tmp[t] = v;
    __syncthreads();
    for (int off = 1; off < 512; off <<= 1) {
        int y = (t >= off) ? tmp[t - off] : 0;
        __syncthreads();
        tmp[t] += y;
        __syncthreads();
    }
    boffs[t] = tmp[t] - v;  // exclusive
    if (t == nb - 1) boffs[nb] = tmp[t];
}

// ---------------------------------------------------------------------------
// Pass 2: one block per bucket. LDS per-node histogram + scan -> offs[];
// scatter src ids directly into the bucket's contiguous (L2-resident) csr
// region. Edge order within a node's segment is arbitrary (see aggr_kernel).
__global__ void build_kernel(const unsigned int* __restrict__ packed,
                             const int* __restrict__ bfill, const int* __restrict__ boffs,
                             int* __restrict__ offs, int* __restrict__ csr, int n) {
    __shared__ int hist[NPB];
    __shared__ int tmp[NPB];
    __shared__ int cur[NPB];
    int b = blockIdx.x, t = threadIdx.x;
    int cnt = min(bfill[b], CAP);
    long long pb = (long long)b * CAP;
    hist[t] = 0;
    __syncthreads();
    for (int i = t; i < cnt; i += NPB)
        atomicAdd(&hist[packed[pb + i] >> 17], 1);
    __syncthreads();
    int v = hist[t];
    tmp[t] = v;
    __syncthreads();
    for (int off = 1; off < NPB; off <<= 1) {
        int y = (t >= off) ? tmp[t - off] : 0;
        __syncthreads();
        tmp[t] += y;
        __syncthreads();
    }
    int excl = tmp[t] - v;
    cur[t] = excl;
    int base = boffs[b];
    int node = b * NPB + t;
    if (node <= n) offs[node] = base + excl;
    __syncthreads();
    for (int i = t; i < cnt; i += NPB) {
        unsigned p = packed[pb + i];
        int dl = p >> 17;
        int lp = atomicAdd(&cur[dl], 1);
        csr[base + lp] = (int)(p & 0x1FFFF);
    }
}

// ---------------------------------------------------------------------------
// Per-node feature transform: h = x @ W; alpha_src = h . a_src; alpha_dst = h . a_dst
template <int NF>
__global__ void feat_kernel(const float* __restrict__ x, const float* __restrict__ W,
                            const float* __restrict__ avs, const float* __restrict__ avd,
                            float* __restrict__ h, float* __restrict__ as,
                            float* __restrict__ ad, int n) {
    __shared__ float sW[NF * 16];
    __shared__ float sa[32];
    int t = threadIdx.x;
    if (t < NF * 16) sW[t] = W[t];
    if (t < 16) sa[t] = avs[t];
    else if (t < 32) sa[t] = avd[t - 16];
    __syncthreads();
    int nid = blockIdx.x * blockDim.x + t;
    if (nid >= n) return;
    float xi[NF];
#pragma unroll
    for (int f = 0; f < NF; ++f) xi[f] = x[(long long)nid * NF + f];
    float hv[16];
    float s1 = 0.f, s2 = 0.f;
#pragma unroll
    for (int k = 0; k < 16; ++k) {
        float acc = 0.f;
#pragma unroll
        for (int f = 0; f < NF; ++f) acc = fmaf(xi[f], sW[f * 16 + k], acc);
        hv[k] = acc;
        s1 = fmaf(acc, sa[k], s1);
        s2 = fmaf(acc, sa[16 + k], s2);
    }
    float4* hp = (float4*)(h + (long long)nid * 16);
    hp[0] = make_float4(hv[0], hv[1], hv[2], hv[3]);
    hp[1] = make_float4(hv[4], hv[5], hv[6], hv[7]);
    hp[2] = make_float4(hv[8], hv[9], hv[10], hv[11]);
    hp[3] = make_float4(hv[12], hv[13], hv[14], hv[15]);
    as[nid] = s1;
    ad[nid] = s2;
}

// ---------------------------------------------------------------------------
// Per-node two-pass softmax aggregation, 16 lanes per node (lane = channel).
// BITWISE ORDER-INDEPENDENT: pass 1 is an exact max (commutative); pass 2
// accumulates numerator/denominator in int64 fixed point (scale 2^42), so the
// result is identical for ANY permutation of each node's edge list. Self loop
// folded in analytically.
__global__ void aggr_kernel(const float* __restrict__ h, const float* __restrict__ as,
                            const float* __restrict__ ad, const int* __restrict__ offs,
                            const int* __restrict__ csr, const float* __restrict__ bias,
                            float* __restrict__ out, int n, int do_relu) {
    int t = threadIdx.x;
    int node = blockIdx.x * 16 + (t >> 4);
    int k = t & 15;
    if (node >= n) return;
    float adn = ad[node];
    float eself = as[node] + adn;
    eself = (eself >= 0.f) ? eself : SLOPE * eself;
    int j0 = offs[node], j1 = offs[node + 1];
    // pass 1: exact max
    float m = eself;
    for (int j = j0; j < j1; ++j) {
        float e = as[csr[j]] + adn;
        e = (e >= 0.f) ? e : SLOPE * e;
        m = fmaxf(m, e);
    }
    // pass 2: fixed-point sums
    float wself = __expf(eself - m);
    long long acc = llrintf(wself * h[(long long)node * 16 + k] * FPSCALE);
    long long den = llrintf(wself * FPSCALE);
    for (int j = j0; j < j1; ++j) {
        int s = csr[j];
        float e = as[s] + adn;
        e = (e >= 0.f) ? e : SLOPE * e;
        float w = __expf(e - m);
        acc += llrintf(w * h[(long long)s * 16 + k] * FPSCALE);
        den += llrintf(w * FPSCALE);
    }
    float o = (float)((double)acc / (double)den) + bias[k];
    if (do_relu) o = fmaxf(o, 0.f);
    out[(long long)node * 16 + k] = o;
}

// ---------------------------------------------------------------------------
extern "C" void kernel_launch(void* const* d_in, const int* in_sizes, int n_in,
                              void* d_out, int out_size, void* d_ws, size_t ws_size,
                              hipStream_t stream) {
    const float* x  = (const float*)d_in[0];
    const void*  ei = d_in[1];
    const float* W1  = (const float*)d_in[2];
    const float* as1 = (const float*)d_in[3];
    const float* ad1 = (const float*)d_in[4];
    const float* b1  = (const float*)d_in[5];
    const float* W2  = (const float*)d_in[6];
    const float* as2 = (const float*)d_in[7];
    const float* ad2 = (const float*)d_in[8];
    const float* b2  = (const float*)d_in[9];
    float* out = (float*)d_out;

    const int n = in_sizes[0] / 14;   // 100000
    const int e = in_sizes[1] / 2;    // 3200000
    const int nb = (n + NPB - 1) / NPB;  // 391 buckets

    char* p = (char*)d_ws;
    auto alloc = [&](size_t bytes) {
        char* r = p;
        p += (bytes + 255) & ~(size_t)255;
        return r;
    };
    int*      flag   = (int*)alloc(256);
    int*      bfill  = (int*)alloc(512 * 4);
    int*      boffs  = (int*)alloc(513 * 4);
    unsigned* packed = (unsigned*)alloc((size_t)nb * CAP * 4);
    int*      offs   = (int*)alloc((size_t)(n + 1) * 4);
    int*      csr    = (int*)alloc((size_t)e * 4);
    float*    h      = (float*)alloc((size_t)n * 16 * 4);
    float*    h1     = (float*)alloc((size_t)n * 16 * 4);
    float*    asb    = (float*)alloc((size_t)n * 4);
    float*    adb    = (float*)alloc((size_t)n * 4);

    hipMemsetAsync(bfill, 0, 512 * 4, stream);
    detect_kernel<<<1, 256, 0, stream>>>((const unsigned int*)ei, flag);
    bin_kernel<<<(e + EPB - 1) / EPB, 256, 0, stream>>>(ei, flag, bfill, packed, e, nb);
    bscan_kernel<<<1, 512, 0, stream>>>(bfill, boffs, nb);
    build_kernel<<<nb, NPB, 0, stream>>>(packed, bfill, boffs, offs, csr, n);

    // Layer 1
    feat_kernel<14><<<(n + 255) / 256, 256, 0, stream>>>(x, W1, as1, ad1, h, asb, adb, n);
    aggr_kernel<<<(n + 15) / 16, 256, 0, stream>>>(h, asb, adb, offs, csr, b1, h1, n, 1);
    // Layer 2
    feat_kernel<16><<<(n + 255) / 256, 256, 0, stream>>>(h1, W2, as2, ad2, h, asb, adb, n);
    aggr_kernel<<<(n + 15) / 16, 256, 0, stream>>>(h, asb, adb, offs, csr, b2, out, n, 0);
}

// Round 5
// 204.161 us; speedup vs baseline: 1.9750x; 1.9750x over previous
//
#include <hip/hip_runtime.h>

static constexpr float SLOPE = 0.2f;

#define NPB 256          // nodes per bucket
#define CAP 10240        // packed-edge capacity per bucket (avg ~8192, >20 sigma margin)
#define EPB 8192         // edges per bin block

// ---------------------------------------------------------------------------
// Monotone float<->uint key for exact atomicMax on floats of either sign.
__device__ __forceinline__ unsigned fkey(float f) {
    unsigned u = __float_as_uint(f);
    return (u & 0x80000000u) ? ~u : (u | 0x80000000u);
}
__device__ __forceinline__ float fdekey(unsigned k) {
    unsigned u = (k & 0x80000000u) ? (k & 0x7FFFFFFFu) : ~k;
    return __uint_as_float(u);
}

// ---------------------------------------------------------------------------
// Detect whether edge_index buffer is int64 or int32 (JAX x64 on/off).
__global__ void detect_kernel(const unsigned int* __restrict__ ei, int* __restrict__ flag) {
    __shared__ int nz;
    if (threadIdx.x == 0) nz = 0;
    __syncthreads();
    if (ei[2 * threadIdx.x + 1] != 0u) atomicOr(&nz, 1);
    __syncthreads();
    if (threadIdx.x == 0) *flag = (nz == 0) ? 1 : 0;
}

__device__ __forceinline__ int load_idx(const void* ei, int is64, long long pos) {
    return is64 ? (int)((const long long*)ei)[pos] : ((const int*)ei)[pos];
}

// ---------------------------------------------------------------------------
// Pass 1: bin edges by dst bucket. Per-block LDS histogram -> bulk reservation
// -> append packed (dst_local<<17 | src) into per-bucket regions. Order within
// a bucket region is schedule-dependent; harmless because aggregation is
// bitwise order-independent (int64 fixed-point sums, exact max).
__global__ void bin_kernel(const void* __restrict__ ei, const int* __restrict__ flag,
                           int* __restrict__ bfill, unsigned int* __restrict__ packed,
                           int e, int nb) {
    __shared__ int hist[512];
    __shared__ int base[512];
    int t = threadIdx.x;
    for (int i = t; i < nb; i += 256) hist[i] = 0;
    __syncthreads();
    long long e0 = (long long)blockIdx.x * EPB;
    int cnt = (int)min((long long)EPB, (long long)e - e0);
    int is64 = *flag;
    // phase A: histogram of dst buckets
    for (int i = t; i < cnt; i += 256) {
        int d = load_idx(ei, is64, (long long)e + e0 + i);
        atomicAdd(&hist[d >> 8], 1);
    }
    __syncthreads();
    // reserve global ranges; reuse hist as local cursor
    for (int i = t; i < nb; i += 256) {
        int c = hist[i];
        base[i] = c ? atomicAdd(&bfill[i], c) : 0;
        hist[i] = 0;
    }
    __syncthreads();
    // phase B: place (dst chunk re-read hits L2)
    for (int i = t; i < cnt; i += 256) {
        int s = load_idx(ei, is64, e0 + i);
        int d = load_idx(ei, is64, (long long)e + e0 + i);
        int bk = d >> 8;
        int lp = atomicAdd(&hist[bk], 1);
        int pos = base[bk] + lp;
        if (pos < CAP)
            packed[(long long)bk * CAP + pos] = ((unsigned)(d & 255) << 17) | (unsigned)s;
    }
}

// ---------------------------------------------------------------------------
// Exclusive scan over bucket fills -> csr base per bucket.
__global__ void bscan_kernel(const int* __restrict__ bfill, int* __restrict__ boffs, int nb) {
    __shared__ int tmp[512];
    int t = threadIdx.x;
    int v = (t < nb) ? min(bfill[t], CAP) : 0;
    tmp[t] = v;
    __syncthreads();
    for (int off = 1; off < 512; off <<= 1) {
        int y = (t >= off) ? tmp[t - off] : 0;
        __syncthreads();
        tmp[t] += y;
        __syncthreads();
    }
    boffs[t] = tmp[t] - v;  // exclusive
    if (t == nb - 1) boffs[nb] = tmp[t];
}

// ---------------------------------------------------------------------------
// Pass 2: one block per bucket. LDS per-node histogram + scan -> offs[];
// scatter src ids directly into the bucket's contiguous (L2-resident) csr
// region. Edge order within a node's segment is arbitrary (see aggr_kernel).
__global__ void build_kernel(const unsigned int* __restrict__ packed,
                             const int* __restrict__ bfill, const int* __restrict__ boffs,
                             int* __restrict__ offs, int* __restrict__ csr, int n) {
    __shared__ int hist[NPB];
    __shared__ int tmp[NPB];
    __shared__ int cur[NPB];
    int b = blockIdx.x, t = threadIdx.x;
    int cnt = min(bfill[b], CAP);
    long long pb = (long long)b * CAP;
    hist[t] = 0;
    __syncthreads();
    for (int i = t; i < cnt; i += NPB)
        atomicAdd(&hist[packed[pb + i] >> 17], 1);
    __syncthreads();
    int v = hist[t];
    tmp[t] = v;
    __syncthreads();
    for (int off = 1; off < NPB; off <<= 1) {
        int y = (t >= off) ? tmp[t - off] : 0;
        __syncthreads();
        tmp[t] += y;
        __syncthreads();
    }
    int excl = tmp[t] - v;
    cur[t] = excl;
    int base = boffs[b];
    int node = b * NPB + t;
    if (node <= n) offs[node] = base + excl;
    __syncthreads();
    for (int i = t; i < cnt; i += NPB) {
        unsigned p = packed[pb + i];
        int dl = p >> 17;
        int lp = atomicAdd(&cur[dl], 1);
        csr[base + lp] = (int)(p & 0x1FFFF);
    }
}

// ---------------------------------------------------------------------------
// Per-node feature transform: h = x @ W; alpha_src = h . a_src; alpha_dst = h . a_dst
// Also computes the EXACT global max of alpha_src (order-free) via uint-keyed
// atomicMax — used by aggr_kernel as a softmax upper bound.
template <int NF>
__global__ void feat_kernel(const float* __restrict__ x, const float* __restrict__ W,
                            const float* __restrict__ avs, const float* __restrict__ avd,
                            float* __restrict__ h, float* __restrict__ as,
                            float* __restrict__ ad, unsigned* __restrict__ gkey, int n) {
    __shared__ float sW[NF * 16];
    __shared__ float sa[32];
    __shared__ float red[256];
    int t = threadIdx.x;
    if (t < NF * 16) sW[t] = W[t];
    if (t < 16) sa[t] = avs[t];
    else if (t < 32) sa[t] = avd[t - 16];
    __syncthreads();
    int nid = blockIdx.x * blockDim.x + t;
    float s1 = -1e30f;
    if (nid < n) {
        float xi[NF];
#pragma unroll
        for (int f = 0; f < NF; ++f) xi[f] = x[(long long)nid * NF + f];
        float hv[16];
        s1 = 0.f;
        float s2 = 0.f;
#pragma unroll
        for (int k = 0; k < 16; ++k) {
            float acc = 0.f;
#pragma unroll
            for (int f = 0; f < NF; ++f) acc = fmaf(xi[f], sW[f * 16 + k], acc);
            hv[k] = acc;
            s1 = fmaf(acc, sa[k], s1);
            s2 = fmaf(acc, sa[16 + k], s2);
        }
        float4* hp = (float4*)(h + (long long)nid * 16);
        hp[0] = make_float4(hv[0], hv[1], hv[2], hv[3]);
        hp[1] = make_float4(hv[4], hv[5], hv[6], hv[7]);
        hp[2] = make_float4(hv[8], hv[9], hv[10], hv[11]);
        hp[3] = make_float4(hv[12], hv[13], hv[14], hv[15]);
        as[nid] = s1;
        ad[nid] = s2;
    }
    red[t] = s1;
    __syncthreads();
    for (int off = 128; off > 0; off >>= 1) {
        if (t < off) red[t] = fmaxf(red[t], red[t + off]);
        __syncthreads();
    }
    if (t == 0) atomicMax(gkey, fkey(red[0]));
}

// ---------------------------------------------------------------------------
// Per-node single-pass softmax aggregation, 16 lanes per node (lane = channel).
// BITWISE ORDER-INDEPENDENT: normalizer m = leaky(gmax_as + adn) is a global
// bound (LeakyReLU is monotone, as[s] <= gmax_as), so no per-node max pass is
// needed and exp args are <= 0. Numerator/denominator accumulate int32-
// converted fixed-point terms into int64 (exact integer addition commutes =>
// identical result for ANY edge permutation). Per-node exponent boost k
// (order-free) keeps den_int >= ~2^20 so quantization error stays ~1e-4 even
// when a node's scores sit far below the global max.
__global__ void aggr_kernel(const float* __restrict__ h, const float* __restrict__ as,
                            const float* __restrict__ ad, const int* __restrict__ offs,
                            const int* __restrict__ csr, const float* __restrict__ bias,
                            const unsigned* __restrict__ gkey,
                            float* __restrict__ out, int n, int do_relu) {
    int t = threadIdx.x;
    int node = blockIdx.x * 16 + (t >> 4);
    int k = t & 15;
    if (node >= n) return;
    float adn = ad[node];
    float gm = fdekey(*gkey) + adn;
    float m = fmaxf(gm, SLOPE * gm);          // leaky(gmax + adn), monotone bound
    float eself = as[node] + adn;
    eself = fmaxf(eself, SLOPE * eself);
    // per-node exponent boost: scale = 2^(21+kb), kb in [0,7]
    float kb = fminf(7.f, fmaxf(0.f, floorf((m - eself) * 1.44269504f)));
    float cc = (21.f + kb) * 0.69314718f - m; // w = exp(e + cc) = exp(e-m)*2^(21+kb)
    float wself = __expf(eself + cc);
    long long den = (int)wself;
    long long acc = (int)(wself * h[(long long)node * 16 + k]);
    int j0 = offs[node], j1 = offs[node + 1];
#pragma unroll 4
    for (int j = j0; j < j1; ++j) {
        int s = csr[j];
        float e = as[s] + adn;
        e = fmaxf(e, SLOPE * e);
        float w = __expf(e + cc);
        den += (int)w;
        acc += (int)(w * h[(long long)s * 16 + k]);
    }
    float o = (float)acc / (float)den + bias[k];
    if (do_relu) o = fmaxf(o, 0.f);
    out[(long long)node * 16 + k] = o;
}

// ---------------------------------------------------------------------------
extern "C" void kernel_launch(void* const* d_in, const int* in_sizes, int n_in,
                              void* d_out, int out_size, void* d_ws, size_t ws_size,
                              hipStream_t stream) {
    const float* x  = (const float*)d_in[0];
    const void*  ei = d_in[1];
    const float* W1  = (const float*)d_in[2];
    const float* as1 = (const float*)d_in[3];
    const float* ad1 = (const float*)d_in[4];
    const float* b1  = (const float*)d_in[5];
    const float* W2  = (const float*)d_in[6];
    const float* as2 = (const float*)d_in[7];
    const float* ad2 = (const float*)d_in[8];
    const float* b2  = (const float*)d_in[9];
    float* out = (float*)d_out;

    const int n = in_sizes[0] / 14;   // 100000
    const int e = in_sizes[1] / 2;    // 3200000
    const int nb = (n + NPB - 1) / NPB;  // 391 buckets

    char* p = (char*)d_ws;
    auto alloc = [&](size_t bytes) {
        char* r = p;
        p += (bytes + 255) & ~(size_t)255;
        return r;
    };
    int*      flag   = (int*)alloc(256);       // [0]=is64 flag, [16]=gkey1, [17]=gkey2
    int*      bfill  = (int*)alloc(512 * 4);
    int*      boffs  = (int*)alloc(513 * 4);
    unsigned* packed = (unsigned*)alloc((size_t)nb * CAP * 4);
    int*      offs   = (int*)alloc((size_t)(n + 1) * 4);
    int*      csr    = (int*)alloc((size_t)e * 4);
    float*    h      = (float*)alloc((size_t)n * 16 * 4);
    float*    h1     = (float*)alloc((size_t)n * 16 * 4);
    float*    asb    = (float*)alloc((size_t)n * 4);
    float*    adb    = (float*)alloc((size_t)n * 4);
    unsigned* gkey1  = (unsigned*)flag + 16;
    unsigned* gkey2  = (unsigned*)flag + 17;

    hipMemsetAsync(flag, 0, 256 + 512 * 4, stream);  // covers flag region + bfill
    detect_kernel<<<1, 256, 0, stream>>>((const unsigned int*)ei, flag);
    bin_kernel<<<(e + EPB - 1) / EPB, 256, 0, stream>>>(ei, flag, bfill, packed, e, nb);
    bscan_kernel<<<1, 512, 0, stream>>>(bfill, boffs, nb);
    build_kernel<<<nb, NPB, 0, stream>>>(packed, bfill, boffs, offs, csr, n);

    // Layer 1
    feat_kernel<14><<<(n + 255) / 256, 256, 0, stream>>>(x, W1, as1, ad1, h, asb, adb, gkey1, n);
    aggr_kernel<<<(n + 15) / 16, 256, 0, stream>>>(h, asb, adb, offs, csr, b1, gkey1, h1, n, 1);
    // Layer 2
    feat_kernel<16><<<(n + 255) / 256, 256, 0, stream>>>(h1, W2, as2, ad2, h, asb, adb, gkey2, n);
    aggr_kernel<<<(n + 15) / 16, 256, 0, stream>>>(h, asb, adb, offs, csr, b2, gkey2, out, n, 0);
}